// Round 4
// baseline (490.387 us; speedup 1.0000x reference)
//
#include <hip/hip_runtime.h>

// RGCN layer, basis-decomposed, atomic-free-in-HBM aggregation via dst-binning.
//
// Identity (validated rounds 2-3, absmax 0.125 pass):
//   xc[n, b*8+j]  = sum_{t<16} x[n, 16j+t] * w_comp[t,b]
//   acc[n, k2] with k2 = b*128 + et*8 + j accumulates norm_e * xc[src_e, b*8+j]
//   out[n,o] = sum_{k2} acc[n,k2] * WbFlat[k2,o]
//
// LDS k-slot: ks = et*32 + j*4 + b  <->  k2 = b*128 + et*8 + j.
// acc lives TRANSPOSED in LDS: accf[ks*20 + node_local], 16 nodes/block.
//
// Workspace layout (51.4 MB):
//   [0,200000)            cnt[50000] i32
//   [200000,200064)       spillcnt i32 (+pad)
//   [200064,6600064)      spill[1.6M] i32
//   [6600064,45000064)    bins[50000][96] uint2 {src|(et<<17), norm bits}
//   [45000064,51400064)   xc[50000][32] f32

#define N_NODES  50000
#define N_EDGES  1600000
#define IN_FEAT  128
#define OUT_FEAT 128
#define NUM_RELS 16
#define NUM_BASES 4
#define XC_K     32
#define BIN_CAP  96
#define NPB      16          // nodes per block in fused kernel
#define ASTRIDE  20          // acc row stride (floats): 16 nodes + 4 pad, 16B-aligned

#define OFF_CNT      0
#define OFF_SPILLCNT 200000
#define OFF_SPILL    200064
#define OFF_BINS     6600064
#define OFF_XC       45000064
#define WS_NEED      51400064

// ---------------- prep: node_precomp (blocks 0..511) + bin_edges (512..2047) --
__global__ __launch_bounds__(256) void prep(
    const float* __restrict__ x, const float* __restrict__ w_comp,
    const int* __restrict__ src, const int* __restrict__ dst,
    const int* __restrict__ etype, const float* __restrict__ norm,
    float* __restrict__ xc, int* __restrict__ cnt, uint2* __restrict__ bins,
    int* __restrict__ spillcnt, int* __restrict__ spill)
{
  if (blockIdx.x < 512) {
    // xc[n, b*8+j] = sum_t x[n,16j+t] * w_comp[t,b]
    const int lane = threadIdx.x & 31;
    const int grp  = threadIdx.x >> 5;
    const int j = lane & 7;
    const int b = lane >> 3;
    float wc[16];
    #pragma unroll
    for (int t = 0; t < 16; ++t) wc[t] = w_comp[t * NUM_BASES + b];
    for (int n = blockIdx.x * 8 + grp; n < N_NODES; n += 512 * 8) {
      const float4* xr = (const float4*)(x + (size_t)n * IN_FEAT) + j * 4;
      float acc = 0.f;
      #pragma unroll
      for (int q = 0; q < 4; ++q) {
        float4 v = xr[q];
        acc += v.x * wc[q*4+0] + v.y * wc[q*4+1]
             + v.z * wc[q*4+2] + v.w * wc[q*4+3];
      }
      xc[n * XC_K + lane] = acc;
    }
  } else {
    // binning, 4 edges per thread via 16B loads
    const int bid = blockIdx.x - 512;                  // 0..1535
    for (int e4 = (bid * 256 + threadIdx.x) * 4; e4 < N_EDGES;
         e4 += 1536 * 256 * 4) {
      const int4   s4 = *(const int4*)&src[e4];
      const int4   d4 = *(const int4*)&dst[e4];
      const int4   t4 = *(const int4*)&etype[e4];
      const float4 n4 = *(const float4*)&norm[e4];
      const int   ss[4] = {s4.x, s4.y, s4.z, s4.w};
      const int   dd[4] = {d4.x, d4.y, d4.z, d4.w};
      const int   tt[4] = {t4.x, t4.y, t4.z, t4.w};
      const float nn[4] = {n4.x, n4.y, n4.z, n4.w};
      #pragma unroll
      for (int q = 0; q < 4; ++q) {
        const int pos = atomicAdd(&cnt[dd[q]], 1);
        if (pos < BIN_CAP) {
          bins[(size_t)dd[q] * BIN_CAP + pos] =
              make_uint2((unsigned)ss[q] | ((unsigned)tt[q] << 17),
                         __float_as_uint(nn[q]));
        } else {
          const int k = atomicAdd(spillcnt, 1);
          if (k < N_EDGES) spill[k] = e4 + q;
        }
      }
    }
  }
}

// ---------------- reduction helpers (k-split combine through LDS) ------------
__device__ inline void red_write(float* accf, int slot, float4 (&ac)[4][2]) {
  const int base = slot * 34;
  #pragma unroll
  for (int nn = 0; nn < 4; ++nn) {
    *(float2*)&accf[base + nn*8 + 0] = make_float2(ac[nn][0].x, ac[nn][0].y);
    *(float2*)&accf[base + nn*8 + 2] = make_float2(ac[nn][0].z, ac[nn][0].w);
    *(float2*)&accf[base + nn*8 + 4] = make_float2(ac[nn][1].x, ac[nn][1].y);
    *(float2*)&accf[base + nn*8 + 6] = make_float2(ac[nn][1].z, ac[nn][1].w);
  }
}
__device__ inline void red_read(const float* accf, int slot, float4 (&ac)[4][2]) {
  const int base = slot * 34;
  #pragma unroll
  for (int nn = 0; nn < 4; ++nn) {
    float2 v0 = *(const float2*)&accf[base + nn*8 + 0];
    float2 v1 = *(const float2*)&accf[base + nn*8 + 2];
    float2 v2 = *(const float2*)&accf[base + nn*8 + 4];
    float2 v3 = *(const float2*)&accf[base + nn*8 + 6];
    ac[nn][0].x += v0.x; ac[nn][0].y += v0.y;
    ac[nn][0].z += v1.x; ac[nn][0].w += v1.y;
    ac[nn][1].x += v2.x; ac[nn][1].y += v2.y;
    ac[nn][1].z += v3.x; ac[nn][1].w += v3.y;
  }
}

// ---------------- fused gather (ds_add_f32) + block GEMM ----------------
// 512 threads = 8 waves, 16 nodes/block (grid 3125, exact).
// Phase A: wave w owns nodes {2w, 2w+1}; its two half-waves share the
//   concatenated edge list (balance), accumulating via LDS atomic fadd into
//   accf[ks*20 + node_local]  (transposed layout).
// Phase B: wave w = k-split ks; lane = ng(4) x og(16); micro-tile 4 nodes x 8 cols;
//   acc read = 1 ds_read_b128 (4 nodes, 16-lane broadcast); w rows wave-uniform.
// Reduction: 3 LDS rounds (4->2->1 waves), wave 0 stores out.
__global__ __launch_bounds__(512, 4) void rgcn_fused(
    const int* __restrict__ cnt, const uint2* __restrict__ bins,
    const float* __restrict__ xc, const float* __restrict__ Wb,
    float* __restrict__ out)
{
  __shared__ float accf[512 * ASTRIDE];   // 40 KB

  const int t    = threadIdx.x;
  const int w    = t >> 6;
  const int lane = t & 63;
  const int h    = lane >> 5;
  const int l5   = lane & 31;
  const int perm = (l5 & 7) * 4 + (l5 >> 3);   // j*4 + b

  // zero acc (each thread 20 floats, 16B-aligned)
  #pragma unroll
  for (int i = 0; i < 5; ++i)
    *(float4*)&accf[t * ASTRIDE + i * 4] = make_float4(0.f, 0.f, 0.f, 0.f);
  __syncthreads();

  const int nodeBase = blockIdx.x * NPB;
  const int n0g = nodeBase + 2 * w;
  const int n1g = n0g + 1;
  int c0 = cnt[n0g]; if (c0 > BIN_CAP) c0 = BIN_CAP;
  int c1 = cnt[n1g]; if (c1 > BIN_CAP) c1 = BIN_CAP;
  const int tot = c0 + c1;

  const uint2* bp0 = bins + (size_t)n0g * BIN_CAP;
  const uint2* bp1 = bins + (size_t)n1g * BIN_CAP;
  const int pb0 = perm * ASTRIDE + 2 * w;   // node-local 2w
  const int pb1 = pb0 + 1;                  // node-local 2w+1

  // ---- phase A, 2-deep pipelined ----
  uint2 bvA = make_uint2(0u, 0u), bvB = make_uint2(0u, 0u);
  if (h < tot)     bvA = (h < c0)     ? bp0[h]            : bp1[h - c0];
  if (h + 2 < tot) bvB = ((h+2) < c0) ? bp0[h+2]          : bp1[h+2-c0];
  int   etA  = (bvA.x >> 17) & 15;
  float nmA  = __uint_as_float(bvA.y);
  int   selA = (h < c0) ? 0 : 1;
  float xcA  = (h < tot) ? xc[(bvA.x & 0x1FFFF) * XC_K + l5] : 0.f;

  for (int gi = h; gi < tot; gi += 2) {
    const int gn = gi + 4;
    uint2 bvC = make_uint2(0u, 0u);
    if (gn < tot) bvC = (gn < c0) ? bp0[gn] : bp1[gn - c0];
    const int gB = gi + 2;
    const int   etB  = (bvB.x >> 17) & 15;
    const float nmB  = __uint_as_float(bvB.y);
    const int   selB = (gB < c0) ? 0 : 1;
    const float xcB  = (gB < tot) ? xc[(bvB.x & 0x1FFFF) * XC_K + l5] : 0.f;
    // consume current edge: LDS atomic fadd (race-free by hardware)
    atomicAdd(&accf[etA * (32 * ASTRIDE) + (selA ? pb1 : pb0)], xcA * nmA);
    bvB = bvC; etA = etB; nmA = nmB; xcA = xcB; selA = selB;
  }
  __syncthreads();

  // ---- phase B: out[16,128] = acc[16,512] @ Wb[512,128], k-split by wave ----
  const int ks = w;
  const int ng = lane & 3;       // nodes ng*4 .. ng*4+3
  const int og = lane >> 2;      // cols og*8 .. og*8+7
  const float* wbase = Wb + og * 8;

  float4 ac[4][2];
  #pragma unroll
  for (int nn = 0; nn < 4; ++nn) {
    ac[nn][0] = make_float4(0.f, 0.f, 0.f, 0.f);
    ac[nn][1] = make_float4(0.f, 0.f, 0.f, 0.f);
  }

  #pragma unroll 4
  for (int q = 0; q < 64; ++q) {
    const int ks2 = ks * 64 + q;
    const int et = ks2 >> 5;
    const int pj = (ks2 >> 2) & 7;
    const int bb = ks2 & 3;
    const int k2 = bb * 128 + et * 8 + pj;          // wave-uniform
    const float4 a4 = *(const float4*)&accf[ks2 * ASTRIDE + ng * 4];
    const float4 w0 = *(const float4*)&wbase[k2 * 128];
    const float4 w1 = *(const float4*)&wbase[k2 * 128 + 4];
    #pragma unroll
    for (int nn = 0; nn < 4; ++nn) {
      const float s = (nn == 0) ? a4.x : (nn == 1) ? a4.y : (nn == 2) ? a4.z : a4.w;
      ac[nn][0].x += s * w0.x; ac[nn][0].y += s * w0.y;
      ac[nn][0].z += s * w0.z; ac[nn][0].w += s * w0.w;
      ac[nn][1].x += s * w1.x; ac[nn][1].y += s * w1.y;
      ac[nn][1].z += s * w1.z; ac[nn][1].w += s * w1.w;
    }
  }

  // ---- combine 8 k-splits: 4 -> 2 -> 1 ----
  __syncthreads();
  if (ks >= 4)             red_write(accf, (ks - 4) * 64 + lane, ac);
  __syncthreads();
  if (ks < 4)              red_read (accf, ks * 64 + lane, ac);
  __syncthreads();
  if (ks == 2 || ks == 3)  red_write(accf, (ks - 2) * 64 + lane, ac);
  __syncthreads();
  if (ks < 2)              red_read (accf, ks * 64 + lane, ac);
  __syncthreads();
  if (ks == 1)             red_write(accf, lane, ac);
  __syncthreads();
  if (ks == 0) {
    red_read(accf, lane, ac);
    #pragma unroll
    for (int nn = 0; nn < 4; ++nn) {
      const int node = nodeBase + ng * 4 + nn;
      *(float4*)(out + (size_t)node * OUT_FEAT + og * 8)     = ac[nn][0];
      *(float4*)(out + (size_t)node * OUT_FEAT + og * 8 + 4) = ac[nn][1];
    }
  }
}

// ---------------- spill fix (bin overflow; normally 0 edges) ----------------
__global__ __launch_bounds__(256) void spill_fix(
    const int* __restrict__ spillcnt, const int* __restrict__ spill,
    const float* __restrict__ xc, const float* __restrict__ Wb,
    const float* __restrict__ norm, const int* __restrict__ src,
    const int* __restrict__ dst, const int* __restrict__ etype,
    float* __restrict__ out)
{
  int cntv = *spillcnt; if (cntv > N_EDGES) cntv = N_EDGES;
  for (int idx = blockIdx.x * blockDim.x + threadIdx.x; idx < cntv;
       idx += gridDim.x * blockDim.x) {
    const int e = spill[idx];
    const int s = src[e], d = dst[e], et = etype[e];
    const float nm = norm[e];
    float m[32];
    #pragma unroll
    for (int l = 0; l < 32; ++l) m[l] = xc[(size_t)s * XC_K + l] * nm;
    for (int o = 0; o < OUT_FEAT; ++o) {
      float a = 0.f;
      #pragma unroll
      for (int l = 0; l < 32; ++l)
        a += m[l] * Wb[(size_t)((l >> 3) * 128 + et * 8 + (l & 7)) * OUT_FEAT + o];
      atomicAdd(&out[(size_t)d * OUT_FEAT + o], a);
    }
  }
}

// ---------------- fallback (tiny d_ws): direct edge -> out atomics ------------
__global__ __launch_bounds__(256) void edge_direct(
    const float* __restrict__ x, const float* __restrict__ W_bases,
    const float* __restrict__ w_comp, const float* __restrict__ norm,
    const int* __restrict__ src, const int* __restrict__ dst,
    const int* __restrict__ etype, float* __restrict__ out)
{
  const int wave = threadIdx.x >> 6;
  const int lane = threadIdx.x & 63;
  const int j = lane & 7;
  const int b = (lane >> 3) & 3;
  float wc[16];
  #pragma unroll
  for (int t = 0; t < 16; ++t) wc[t] = w_comp[t * NUM_BASES + b];
  for (int e = blockIdx.x * 4 + wave; e < N_EDGES; e += gridDim.x * 4) {
    const int s = src[e], d = dst[e], et = etype[e];
    const float nm = norm[e];
    const float4* xr = (const float4*)(x + (size_t)s * IN_FEAT) + j * 4;
    float m = 0.f;
    #pragma unroll
    for (int q = 0; q < 4; ++q) {
      float4 v = xr[q];
      m += v.x * wc[q*4+0] + v.y * wc[q*4+1]
         + v.z * wc[q*4+2] + v.w * wc[q*4+3];
    }
    m *= nm;
    float acc0 = 0.f, acc1 = 0.f;
    #pragma unroll
    for (int p = 0; p < 32; ++p) {
      float mv = __shfl(m, p, 64);
      const float* Wr = W_bases + (size_t)((p >> 3) * 128 + et * 8 + (p & 7)) * OUT_FEAT;
      acc0 += mv * Wr[lane];
      acc1 += mv * Wr[64 + lane];
    }
    atomicAdd(out + (size_t)d * OUT_FEAT + lane, acc0);
    atomicAdd(out + (size_t)d * OUT_FEAT + 64 + lane, acc1);
  }
}

extern "C" void kernel_launch(void* const* d_in, const int* in_sizes, int n_in,
                              void* d_out, int out_size, void* d_ws, size_t ws_size,
                              hipStream_t stream) {
  const float* x       = (const float*)d_in[0];
  const float* W_bases = (const float*)d_in[1];   // flat [512][128]
  const float* w_comp  = (const float*)d_in[2];
  const float* norm    = (const float*)d_in[3];
  const int*   src     = (const int*)d_in[4];
  const int*   dst     = (const int*)d_in[5];
  const int*   etype   = (const int*)d_in[6];
  float* out = (float*)d_out;

  if (ws_size >= (size_t)WS_NEED) {
    char* ws = (char*)d_ws;
    int*   cntp     = (int*)(ws + OFF_CNT);
    int*   spillcnt = (int*)(ws + OFF_SPILLCNT);
    int*   spill    = (int*)(ws + OFF_SPILL);
    uint2* bins     = (uint2*)(ws + OFF_BINS);
    float* xc       = (float*)(ws + OFF_XC);

    hipMemsetAsync(cntp, 0, 200064, stream);   // cnt + spillcnt
    prep<<<2048, 256, 0, stream>>>(x, w_comp, src, dst, etype, norm,
                                   xc, cntp, bins, spillcnt, spill);
    rgcn_fused<<<N_NODES / NPB, 512, 0, stream>>>(cntp, bins, xc, W_bases, out);
    spill_fix<<<16, 256, 0, stream>>>(spillcnt, spill, xc, W_bases,
                                      norm, src, dst, etype, out);
  } else {
    hipMemsetAsync(out, 0, (size_t)out_size * sizeof(float), stream);
    edge_direct<<<8192, 256, 0, stream>>>(x, W_bases, w_comp, norm,
                                          src, dst, etype, out);
  }
}

// Round 5
// 451.791 us; speedup vs baseline: 1.0854x; 1.0854x over previous
//
#include <hip/hip_runtime.h>

// RGCN layer, basis-decomposed, atomic-free LDS aggregation via dst-binning.
//
// Identity (validated rounds 2-4, passed):
//   xc[n, b*8+j]  = sum_{t<16} x[n, 16j+t] * w_comp[t,b]
//   acc[n, k2], k2 = b*128 + et*8 + j, accumulates norm_e * xc[src_e, b*8+j]
//   out[n,o] = sum_{k2} acc[n,k2] * WbFlat[k2,o]
//
// LDS physical slot within a node row: s = et*32 + j*4 + b  (0..511)
//   inverse: b = s&3, j = (s>>2)&7, et = s>>5  ->  k2 = b*128 + et*8 + j
// acc layout: node-major accf[ln*516 + s], ln = 0..15 (RS=516: rows 4*516=2064
// words apart == 16 mod 32 banks -> phase-B 4-row reads are only 2-way aliased).
//
// Workspace layout (51.4 MB):
//   [0,200000)            cnt[50000] i32
//   [200000,200064)       spillcnt i32 (+pad)
//   [200064,6600064)      spill[1.6M] i32
//   [6600064,45000064)    bins[50000][96] uint2 {src|(et<<17), norm bits}
//   [45000064,51400064)   xc[50000][32] f32

#define N_NODES  50000
#define N_EDGES  1600000
#define IN_FEAT  128
#define OUT_FEAT 128
#define NUM_RELS 16
#define NUM_BASES 4
#define XC_K     32
#define BIN_CAP  96
#define NPB      16          // nodes per block in fused kernel
#define RS       516         // acc row stride in floats (512 + 4 pad)
#define ACCF_WORDS 8704      // max(16*516=8256, reduction 256*34=8704)

#define OFF_CNT      0
#define OFF_SPILLCNT 200000
#define OFF_SPILL    200064
#define OFF_BINS     6600064
#define OFF_XC       45000064
#define WS_NEED      51400064

// ---------------- prep: every block does precomp slice THEN binning slice ----
__global__ __launch_bounds__(256) void prep(
    const float* __restrict__ x, const float* __restrict__ w_comp,
    const int* __restrict__ src, const int* __restrict__ dst,
    const int* __restrict__ etype, const float* __restrict__ norm,
    float* __restrict__ xc, int* __restrict__ cnt, uint2* __restrict__ bins,
    int* __restrict__ spillcnt, int* __restrict__ spill)
{
  // part 1: xc[n, b*8+j] = sum_t x[n,16j+t] * w_comp[t,b]
  {
    const int lane = threadIdx.x & 31;
    const int grp  = threadIdx.x >> 5;
    const int j = lane & 7;
    const int b = lane >> 3;
    float wc[16];
    #pragma unroll
    for (int t = 0; t < 16; ++t) wc[t] = w_comp[t * NUM_BASES + b];
    for (int n = blockIdx.x * 8 + grp; n < N_NODES; n += 2048 * 8) {
      const float4* xr = (const float4*)(x + (size_t)n * IN_FEAT) + j * 4;
      float acc = 0.f;
      #pragma unroll
      for (int q = 0; q < 4; ++q) {
        float4 v = xr[q];
        acc += v.x * wc[q*4+0] + v.y * wc[q*4+1]
             + v.z * wc[q*4+2] + v.w * wc[q*4+3];
      }
      xc[n * XC_K + lane] = acc;
    }
  }
  // part 2: binning, 4 edges per thread via 16B loads (single pass: 2048*256*4 >= E)
  {
    const int e4 = (blockIdx.x * 256 + threadIdx.x) * 4;
    if (e4 < N_EDGES) {
      const int4   s4 = *(const int4*)&src[e4];
      const int4   d4 = *(const int4*)&dst[e4];
      const int4   t4 = *(const int4*)&etype[e4];
      const float4 n4 = *(const float4*)&norm[e4];
      const int   ss[4] = {s4.x, s4.y, s4.z, s4.w};
      const int   dd[4] = {d4.x, d4.y, d4.z, d4.w};
      const int   tt[4] = {t4.x, t4.y, t4.z, t4.w};
      const float nn[4] = {n4.x, n4.y, n4.z, n4.w};
      #pragma unroll
      for (int q = 0; q < 4; ++q) {
        const int pos = atomicAdd(&cnt[dd[q]], 1);
        if (pos < BIN_CAP) {
          bins[(size_t)dd[q] * BIN_CAP + pos] =
              make_uint2((unsigned)ss[q] | ((unsigned)tt[q] << 17),
                         __float_as_uint(nn[q]));
        } else {
          const int k = atomicAdd(spillcnt, 1);
          if (k < N_EDGES) spill[k] = e4 + q;
        }
      }
    }
  }
}

// ---------------- reduction helpers (k-split combine through LDS) ------------
__device__ inline void red_write(float* accf, int slot, float4 (&ac)[4][2]) {
  const int base = slot * 34;
  #pragma unroll
  for (int nn = 0; nn < 4; ++nn) {
    *(float2*)&accf[base + nn*8 + 0] = make_float2(ac[nn][0].x, ac[nn][0].y);
    *(float2*)&accf[base + nn*8 + 2] = make_float2(ac[nn][0].z, ac[nn][0].w);
    *(float2*)&accf[base + nn*8 + 4] = make_float2(ac[nn][1].x, ac[nn][1].y);
    *(float2*)&accf[base + nn*8 + 6] = make_float2(ac[nn][1].z, ac[nn][1].w);
  }
}
__device__ inline void red_read(const float* accf, int slot, float4 (&ac)[4][2]) {
  const int base = slot * 34;
  #pragma unroll
  for (int nn = 0; nn < 4; ++nn) {
    float2 v0 = *(const float2*)&accf[base + nn*8 + 0];
    float2 v1 = *(const float2*)&accf[base + nn*8 + 2];
    float2 v2 = *(const float2*)&accf[base + nn*8 + 4];
    float2 v3 = *(const float2*)&accf[base + nn*8 + 6];
    ac[nn][0].x += v0.x; ac[nn][0].y += v0.y;
    ac[nn][0].z += v1.x; ac[nn][0].w += v1.y;
    ac[nn][1].x += v2.x; ac[nn][1].y += v2.y;
    ac[nn][1].z += v3.x; ac[nn][1].w += v3.y;
  }
}

__device__ inline float selb(const float4& v, int bb) {
  return bb == 0 ? v.x : bb == 1 ? v.y : bb == 2 ? v.z : v.w;
}

// ---------------- fused gather (non-atomic LDS RMW) + block GEMM ----------------
// 512 threads = 8 waves, 16 nodes/block (grid 3125 exact).
// Phase A: HALF-WAVE (w,h) exclusively owns node ln = 2w+h -> plain += into its
//   row, conflict-free (32 consecutive slots = 32 banks). Pair-wise bins
//   (uint4 = 2 edges), depth-2 pipeline, no branches (v=0 + clamped src).
// Phase B: wave = k-split; lane = ng(4 nodes) x og(8 cols); acc read along k
//   (ds_read_b128, 2-way max); Wb rows wave-uniform. Tree-reduce 8 splits.
__global__ __launch_bounds__(512, 8) void rgcn_fused(
    const int* __restrict__ cnt, const uint2* __restrict__ bins,
    const float* __restrict__ xc, const float* __restrict__ Wb,
    float* __restrict__ out)
{
  __shared__ float accf[ACCF_WORDS];   // 34 KB -> 4 blocks/CU

  const int t    = threadIdx.x;
  const int w    = t >> 6;
  const int lane = t & 63;
  const int h    = lane >> 5;
  const int l5   = lane & 31;
  const int perm = (l5 & 7) * 4 + (l5 >> 3);   // j*4 + b

  // zero accf (2176 float4 over 512 threads)
  for (int i = t; i < ACCF_WORDS / 4; i += 512)
    ((float4*)accf)[i] = make_float4(0.f, 0.f, 0.f, 0.f);
  __syncthreads();

  const int nodeBase = blockIdx.x * NPB;
  const int ln = w * 2 + h;                    // local node 0..15
  const int n  = nodeBase + ln;
  int c = cnt[n]; c = c > BIN_CAP ? BIN_CAP : c;
  const int cmax   = max(c, __shfl_xor(c, 32));
  const int npairs = (cmax + 1) >> 1;

  const uint4* bp4 = (const uint4*)(bins + (size_t)n * BIN_CAP);
  const int awb = ln * RS + perm;              // base word for this lane

  // ---- phase A, depth-2 pipeline over edge pairs ----
  uint4 q0 = bp4[0];
  int s00 = (0 < c) ? (int)(q0.x & 0x1FFFF) : 0;
  int s01 = (1 < c) ? (int)(q0.z & 0x1FFFF) : 0;
  float xa = xc[(size_t)s00 * XC_K + l5];
  float xb = xc[(size_t)s01 * XC_K + l5];
  uint4 q1 = bp4[1];

  for (int p = 0; p < npairs; ++p) {
    // prefetch: xc of pair p+1, bins of pair p+2
    const int i0 = 2 * (p + 1);
    const int s10 = (i0     < c) ? (int)(q1.x & 0x1FFFF) : 0;
    const int s11 = (i0 + 1 < c) ? (int)(q1.z & 0x1FFFF) : 0;
    const float ya = xc[(size_t)s10 * XC_K + l5];
    const float yb = xc[(size_t)s11 * XC_K + l5];
    const uint4 q2 = bp4[p + 2];
    // consume pair p (non-atomic: this half-wave exclusively owns row ln)
    const int e0 = 2 * p;
    const float v0 = (e0     < c) ? xa * __uint_as_float(q0.y) : 0.f;
    const float v1 = (e0 + 1 < c) ? xb * __uint_as_float(q0.w) : 0.f;
    const int et0 = (int)((q0.x >> 17) & 15);
    const int et1 = (int)((q0.z >> 17) & 15);
    accf[awb + et0 * 32] += v0;
    accf[awb + et1 * 32] += v1;
    q0 = q1; q1 = q2; xa = ya; xb = yb;
  }
  __syncthreads();

  // ---- phase B: out[16,128] = acc[16,512] @ Wb[512,128], k-split by wave ----
  const int ks = w;
  const int ng = lane & 3;       // nodes ng*4 .. ng*4+3
  const int og = lane >> 2;      // cols og*8 .. og*8+7
  const float* wbase = Wb + og * 8;

  float4 ac[4][2];
  #pragma unroll
  for (int nn = 0; nn < 4; ++nn) {
    ac[nn][0] = make_float4(0.f, 0.f, 0.f, 0.f);
    ac[nn][1] = make_float4(0.f, 0.f, 0.f, 0.f);
  }

  #pragma unroll 4
  for (int q = 0; q < 16; ++q) {
    const int k0 = ks * 64 + q * 4;                  // slot base; b = 0..3 inside
    const int r0 = (k0 >> 5) * 8 + ((k0 >> 2) & 7);  // et*8 + j
    float4 a4[4];
    #pragma unroll
    for (int nn = 0; nn < 4; ++nn)
      a4[nn] = *(const float4*)&accf[(ng * 4 + nn) * RS + k0];
    #pragma unroll
    for (int bb = 0; bb < 4; ++bb) {
      const float* wr = wbase + (size_t)(bb * 128 + r0) * 128;
      const float4 w0 = *(const float4*)wr;
      const float4 w1 = *(const float4*)(wr + 4);
      #pragma unroll
      for (int nn = 0; nn < 4; ++nn) {
        const float s = selb(a4[nn], bb);
        ac[nn][0].x += s * w0.x; ac[nn][0].y += s * w0.y;
        ac[nn][0].z += s * w0.z; ac[nn][0].w += s * w0.w;
        ac[nn][1].x += s * w1.x; ac[nn][1].y += s * w1.y;
        ac[nn][1].z += s * w1.z; ac[nn][1].w += s * w1.w;
      }
    }
  }

  // ---- combine 8 k-splits: 4 -> 2 -> 1 (proven round-4 structure) ----
  __syncthreads();
  if (ks >= 4)             red_write(accf, (ks - 4) * 64 + lane, ac);
  __syncthreads();
  if (ks < 4)              red_read (accf, ks * 64 + lane, ac);
  __syncthreads();
  if (ks == 2 || ks == 3)  red_write(accf, (ks - 2) * 64 + lane, ac);
  __syncthreads();
  if (ks < 2)              red_read (accf, ks * 64 + lane, ac);
  __syncthreads();
  if (ks == 1)             red_write(accf, lane, ac);
  __syncthreads();
  if (ks == 0) {
    red_read(accf, lane, ac);
    #pragma unroll
    for (int nn = 0; nn < 4; ++nn) {
      const int node = nodeBase + ng * 4 + nn;
      *(float4*)(out + (size_t)node * OUT_FEAT + og * 8)     = ac[nn][0];
      *(float4*)(out + (size_t)node * OUT_FEAT + og * 8 + 4) = ac[nn][1];
    }
  }
}

// ---------------- spill fix (bin overflow; normally 0 edges) ----------------
__global__ __launch_bounds__(256) void spill_fix(
    const int* __restrict__ spillcnt, const int* __restrict__ spill,
    const float* __restrict__ xc, const float* __restrict__ Wb,
    const float* __restrict__ norm, const int* __restrict__ src,
    const int* __restrict__ dst, const int* __restrict__ etype,
    float* __restrict__ out)
{
  int cntv = *spillcnt; if (cntv > N_EDGES) cntv = N_EDGES;
  for (int idx = blockIdx.x * blockDim.x + threadIdx.x; idx < cntv;
       idx += gridDim.x * blockDim.x) {
    const int e = spill[idx];
    const int s = src[e], d = dst[e], et = etype[e];
    const float nm = norm[e];
    float m[32];
    #pragma unroll
    for (int l = 0; l < 32; ++l) m[l] = xc[(size_t)s * XC_K + l] * nm;
    for (int o = 0; o < OUT_FEAT; ++o) {
      float a = 0.f;
      #pragma unroll
      for (int l = 0; l < 32; ++l)
        a += m[l] * Wb[(size_t)((l >> 3) * 128 + et * 8 + (l & 7)) * OUT_FEAT + o];
      atomicAdd(&out[(size_t)d * OUT_FEAT + o], a);
    }
  }
}

// ---------------- fallback (tiny d_ws): direct edge -> out atomics ------------
__global__ __launch_bounds__(256) void edge_direct(
    const float* __restrict__ x, const float* __restrict__ W_bases,
    const float* __restrict__ w_comp, const float* __restrict__ norm,
    const int* __restrict__ src, const int* __restrict__ dst,
    const int* __restrict__ etype, float* __restrict__ out)
{
  const int wave = threadIdx.x >> 6;
  const int lane = threadIdx.x & 63;
  const int j = lane & 7;
  const int b = (lane >> 3) & 3;
  float wc[16];
  #pragma unroll
  for (int t = 0; t < 16; ++t) wc[t] = w_comp[t * NUM_BASES + b];
  for (int e = blockIdx.x * 4 + wave; e < N_EDGES; e += gridDim.x * 4) {
    const int s = src[e], d = dst[e], et = etype[e];
    const float nm = norm[e];
    const float4* xr = (const float4*)(x + (size_t)s * IN_FEAT) + j * 4;
    float m = 0.f;
    #pragma unroll
    for (int q = 0; q < 4; ++q) {
      float4 v = xr[q];
      m += v.x * wc[q*4+0] + v.y * wc[q*4+1]
         + v.z * wc[q*4+2] + v.w * wc[q*4+3];
    }
    m *= nm;
    float acc0 = 0.f, acc1 = 0.f;
    #pragma unroll
    for (int p = 0; p < 32; ++p) {
      float mv = __shfl(m, p, 64);
      const float* Wr = W_bases + (size_t)((p >> 3) * 128 + et * 8 + (p & 7)) * OUT_FEAT;
      acc0 += mv * Wr[lane];
      acc1 += mv * Wr[64 + lane];
    }
    atomicAdd(out + (size_t)d * OUT_FEAT + lane, acc0);
    atomicAdd(out + (size_t)d * OUT_FEAT + 64 + lane, acc1);
  }
}

extern "C" void kernel_launch(void* const* d_in, const int* in_sizes, int n_in,
                              void* d_out, int out_size, void* d_ws, size_t ws_size,
                              hipStream_t stream) {
  const float* x       = (const float*)d_in[0];
  const float* W_bases = (const float*)d_in[1];   // flat [512][128]
  const float* w_comp  = (const float*)d_in[2];
  const float* norm    = (const float*)d_in[3];
  const int*   src     = (const int*)d_in[4];
  const int*   dst     = (const int*)d_in[5];
  const int*   etype   = (const int*)d_in[6];
  float* out = (float*)d_out;

  if (ws_size >= (size_t)WS_NEED) {
    char* ws = (char*)d_ws;
    int*   cntp     = (int*)(ws + OFF_CNT);
    int*   spillcnt = (int*)(ws + OFF_SPILLCNT);
    int*   spill    = (int*)(ws + OFF_SPILL);
    uint2* bins     = (uint2*)(ws + OFF_BINS);
    float* xc       = (float*)(ws + OFF_XC);

    hipMemsetAsync(cntp, 0, 200064, stream);   // cnt + spillcnt
    prep<<<2048, 256, 0, stream>>>(x, w_comp, src, dst, etype, norm,
                                   xc, cntp, bins, spillcnt, spill);
    rgcn_fused<<<N_NODES / NPB, 512, 0, stream>>>(cntp, bins, xc, W_bases, out);
    spill_fix<<<16, 256, 0, stream>>>(spillcnt, spill, xc, W_bases,
                                      norm, src, dst, etype, out);
  } else {
    hipMemsetAsync(out, 0, (size_t)out_size * sizeof(float), stream);
    edge_direct<<<8192, 256, 0, stream>>>(x, W_bases, w_comp, norm,
                                          src, dst, etype, out);
  }
}